// Round 6
// baseline (736.308 us; speedup 1.0000x reference)
//
#include <hip/hip_runtime.h>
#include <hip/hip_bf16.h>

// StyleBlock: B=16, C_IN=512, C_OUT=512, D_LATENT=512, H=W=64, K=3
// R4 (verified, 270us, MfmaUtil 52%): 8-wave 512-thr, A in LDS (XOR-swizzled),
// B direct-global (L1-cached, 4-way shared). R5 (B into LDS) REGRESSED to
// 296us: exposed vmcnt(0) drain tripled + LDS pipe saturated. Reverted.
// R6 (this round): R4 structure + A DOUBLE-BUFFER (2x42240=84480 B LDS),
// prefetch A[c+1] issued before inner loop; in-order vmcnt means the B-loads
// of chunk c drain the A-prefetch for free -> single barrier per chunk,
// staging fully hidden under MFMA.

#define B_    16
#define CIN   512
#define COUT  512
#define DLAT  512
#define H_    64
#define W_    64

#define ABUF  42240            // 10 rows * 66 px * 4 granules * 16B
#define LDS_BYTES (2 * ABUF)

constexpr float LIN_COEF  = 0.04419417382415922f;   // 1/sqrt(512)
constexpr float CONV_COEF = 0.014731391274719739f;  // 1/sqrt(512*9)

typedef __attribute__((ext_vector_type(8))) short short8;
typedef __attribute__((ext_vector_type(4))) float f32x4;

__device__ __forceinline__ void gl2lds16(const void* g, void* l) {
  __builtin_amdgcn_global_load_lds(
      (const __attribute__((address_space(1))) unsigned*)g,
      (__attribute__((address_space(3))) unsigned*)l, 16, 0, 0);
}

// =============== pre-kernel 1: style | wsq  (3072 blocks) =========================
__global__ __launch_bounds__(256) void pre1(
    const float* __restrict__ w, const float* __restrict__ style_w,
    const float* __restrict__ style_b, const float* __restrict__ conv_w,
    float* __restrict__ style, float* __restrict__ wsq) {
  const int bid = blockIdx.x, tid = threadIdx.x;
  if (bid < 2048) {            // ---- style[b,c] ----
    int gw = bid * 4 + (tid >> 6), lane = tid & 63;
    int b = gw >> 9, c = gw & 511;
    const float* wp = w + b * DLAT;
    const float* sw = style_w + c * DLAT;
    float v = 0.f;
    for (int d = lane; d < DLAT; d += 64) v = fmaf(wp[d], sw[d], v);
    #pragma unroll
    for (int off = 32; off > 0; off >>= 1) v += __shfl_down(v, off, 64);
    if (lane == 0) style[b * CIN + c] = fmaf(v, LIN_COEF, style_b[c]);
  } else {                     // ---- wsq[o,i] ----
    int idx = (bid - 2048) * 256 + tid;
    const float* p = conv_w + (size_t)idx * 9;
    float s = 0.f;
    #pragma unroll
    for (int t = 0; t < 9; ++t) s = fmaf(p[t], p[t], s);
    wsq[idx] = s;
  }
}

// ====== pre-kernel 2: scale_bo | wtp2 | border-zero | xmod  (10816 blocks) ========
#define LSTR 136
__global__ __launch_bounds__(256) void pre2(
    const float* __restrict__ x, const float* __restrict__ style,
    const float* __restrict__ wsq, const float* __restrict__ conv_w,
    float* __restrict__ scale_bo, __hip_bfloat16* __restrict__ wtp2,
    __hip_bfloat16* __restrict__ xt) {
  __shared__ __align__(16) char sm2[18432];
  const int bid = blockIdx.x, tid = threadIdx.x;
  if (bid < 2048) {            // ---- scale_bo[b,o] ----
    int gw = bid * 4 + (tid >> 6), lane = tid & 63;
    int b = gw >> 9, o = gw & 511;
    const float* st = style + b * CIN;
    const float* wq = wsq + o * CIN;
    float v = 0.f;
    for (int i = lane; i < CIN; i += 64) { float s = st[i]; v = fmaf(s * s, wq[i], v); }
    #pragma unroll
    for (int off = 32; off > 0; off >>= 1) v += __shfl_down(v, off, 64);
    if (lane == 0)
      scale_bo[b * COUT + o] = CONV_COEF * rsqrtf(fmaf(CONV_COEF * CONV_COEF, v, 1e-8f));
  } else if (bid < 2560) {     // ---- wtp2[chunk][pos][kq][o][8] bf16 ----
    int o = bid - 2048;
    float* lw = (float*)sm2;
    for (int j = tid; j < CIN * 9; j += 256) lw[j] = conv_w[(size_t)o * (CIN * 9) + j];
    __syncthreads();
    for (int g = tid; g < 576; g += 256) {   // 16 chunks * 9 pos * 4 kq
      int chunk = g / 36, rem = g - chunk * 36, pos = rem >> 2, kqq = rem & 3;
      short8 v;
      #pragma unroll
      for (int e = 0; e < 8; ++e) {
        int ic = chunk * 32 + kqq * 8 + e;
        ((__hip_bfloat16*)&v)[e] = __float2bfloat16(lw[ic * 9 + pos]);
      }
      ((short8*)wtp2)[(size_t)g * 512 + o] = v;
    }
  } else if (bid < 6720) {     // ---- zero x_t halo border ----
    int idx = bid - 2560;      // 16*260
    int b = idx / 260, pb = idx - b * 260;
    int hh, ww;
    if (pb < 66)       { hh = 0;  ww = pb; }
    else if (pb < 132) { hh = 65; ww = pb - 66; }
    else if (pb < 196) { hh = pb - 132 + 1; ww = 0; }
    else               { hh = pb - 196 + 1; ww = 65; }
    unsigned* p = (unsigned*)(xt + (((size_t)b * 66 + hh) * 66 + ww) * CIN);
    p[tid] = 0u;
  } else {                     // ---- x_t[b][h+1][w+1][ic] = bf16(x * style) ----
    int idx = bid - 6720;      // 16*64*4
    int b = idx >> 8, rem = idx & 255, h = rem >> 2, ic0 = (rem & 3) * 128;
    __hip_bfloat16* ls = (__hip_bfloat16*)sm2;      // [64 w][LSTR ic]
    for (int j = tid; j < 2048; j += 256) {         // 128 ic x 16 w-quads
      int i = j >> 4, wq = j & 15;
      const float4 xv = *(const float4*)&x[(((size_t)b * CIN + ic0 + i) * H_ + h) * W_ + wq * 4];
      float st = style[b * CIN + ic0 + i];
      ls[(wq * 4 + 0) * LSTR + i] = __float2bfloat16(xv.x * st);
      ls[(wq * 4 + 1) * LSTR + i] = __float2bfloat16(xv.y * st);
      ls[(wq * 4 + 2) * LSTR + i] = __float2bfloat16(xv.z * st);
      ls[(wq * 4 + 3) * LSTR + i] = __float2bfloat16(xv.w * st);
    }
    __syncthreads();
    for (int j = tid; j < 1024; j += 256) {
      int ww = j >> 4, part = j & 15;
      __hip_bfloat16* dst = xt + (((size_t)b * 66 + h + 1) * 66 + (ww + 1)) * CIN + ic0 + part * 8;
      *(short8*)dst = *(const short8*)(ls + ww * LSTR + part * 8);
    }
  }
}

// ========== main conv: block = 8 rows x 64 px x 128 o, 8 waves (512 thr) ==========
// Wave (wr=wv>>1, wc=wv&1): rows h0+wr*2..+1, o-half wc. Per-wave tile 128px x 64o
// = 8x4 MFMA 16x16x32 frags, acc 128 VGPR. B direct-global (L1-cached).
// LDS: DOUBLE-BUFFERED A-tile (2 x 10 rows x 66 px x 32 ic, XOR-swizzled).
// One barrier per chunk: prefetch A[c+1] issued before compute; in-order vmcnt
// means chunk-c B loads force the prefetch along; __syncthreads' vmcnt(0) drain
// is ~free by then.
__global__ __launch_bounds__(512, 2) void conv_mfma(
    const __hip_bfloat16* __restrict__ xt, const __hip_bfloat16* __restrict__ wtp2,
    const float* __restrict__ scale_bo, const float* __restrict__ noise,
    const float* __restrict__ scale_noise, const float* __restrict__ bias,
    float* __restrict__ out) {
  __shared__ __align__(16) char smem[LDS_BYTES];

  const int tid = threadIdx.x, lane = tid & 63, wv = tid >> 6;
  const int mrow = lane & 15, kq = lane >> 4;
  const int wr = wv >> 1, wc = wv & 1;
  const int b  = blockIdx.x >> 3;
  const int h0 = (blockIdx.x & 7) << 3;      // 8 output rows per block
  const int oo0 = (blockIdx.y << 7) + (wc << 6);
  const int r0 = h0 + (wr << 1);             // wave's first output row

  // ---- A staging: granule t = wv*330 + i*64 + lane; pixel p=t>>2, slot s=t&3,
  //      holds ic-group q = s ^ ((p>>1)&3)  (XOR bank swizzle) ----
  const size_t xbase = ((size_t)(b * 66 + h0)) * (66 * 512);
  int xoff[6];
  #pragma unroll
  for (int i = 0; i < 6; ++i) {
    int r = i * 64 + lane;                   // within-wave granule rank
    if (r < 330) {
      int t = wv * 330 + r;
      int p = t >> 2, s = t & 3;
      int q = s ^ ((p >> 1) & 3);
      xoff[i] = p * 512 + q * 8;
    } else xoff[i] = -1;
  }
  const int ldst = wv * 5280;                // (wv*330)*16

  f32x4 acc[8][4] = {};        // [ms][ns]
  int pbase[8];
  #pragma unroll
  for (int ms = 0; ms < 8; ++ms)
    pbase[ms] = ((wr << 1) + (ms >> 2)) * 66 + (ms & 3) * 16 + mrow;

  const short8* bbase = (const short8*)wtp2 + (kq * 512 + oo0 + mrow);

  // ---- prologue: stage chunk 0 into buf 0 ----
  #pragma unroll
  for (int i = 0; i < 6; ++i)
    if (xoff[i] >= 0)
      gl2lds16(xt + xbase + xoff[i], smem + ldst + i * 1024);
  __syncthreads();                           // vmcnt(0) drain + barrier

  for (int c = 0; c < 16; ++c) {
    const int cur = (c & 1) ? ABUF : 0;
    if (c < 15) {                            // issue A[c+1] prefetch (no wait)
      const int nxt = (c & 1) ? 0 : ABUF;
      const int ic1 = (c + 1) << 5;
      #pragma unroll
      for (int i = 0; i < 6; ++i)
        if (xoff[i] >= 0)
          gl2lds16(xt + xbase + xoff[i] + ic1, smem + nxt + ldst + i * 1024);
    }

    const int ch9 = c * 9;
    #pragma unroll
    for (int ky = 0; ky < 3; ++ky) {
      #pragma unroll
      for (int kx = 0; kx < 3; ++kx) {
        const short8* bp = bbase + (size_t)(ch9 + ky * 3 + kx) * 2048;
        short8 bf0 = bp[0], bf1 = bp[16], bf2 = bp[32], bf3 = bp[48];
        short8 af[8];
        #pragma unroll
        for (int ms = 0; ms < 8; ++ms) {
          int p = pbase[ms] + ky * 66 + kx;
          int s = kq ^ ((p >> 1) & 3);
          af[ms] = *(const short8*)(smem + cur + p * 64 + s * 16);
        }
        #pragma unroll
        for (int ms = 0; ms < 8; ++ms) {
          acc[ms][0] = __builtin_amdgcn_mfma_f32_16x16x32_bf16(af[ms], bf0, acc[ms][0], 0, 0, 0);
          acc[ms][1] = __builtin_amdgcn_mfma_f32_16x16x32_bf16(af[ms], bf1, acc[ms][1], 0, 0, 0);
          acc[ms][2] = __builtin_amdgcn_mfma_f32_16x16x32_bf16(af[ms], bf2, acc[ms][2], 0, 0, 0);
          acc[ms][3] = __builtin_amdgcn_mfma_f32_16x16x32_bf16(af[ms], bf3, acc[ms][3], 0, 0, 0);
        }
      }
    }
    __syncthreads();   // drains this iter's prefetch (free) + guards buf reuse
  }

  // ---- epilogue: per-wave LDS transpose -> coalesced stores ----
  float* ep = (float*)smem + wv * 1088;        // 64 x 17 f32 per wave (private)
  const float sn = scale_noise[0];

  #pragma unroll
  for (int r = 0; r < 2; ++r) {
    const int h = r0 + r;
    const float nz = sn * noise[((size_t)b * H_ + h) * W_ + lane];
    for (int ns = 0; ns < 4; ++ns) {
      #pragma unroll
      for (int m4 = 0; m4 < 4; ++m4) {
        int ms = r * 4 + m4;
        int prow = m4 * 16 + kq * 4;           // pixel col within row
        #pragma unroll
        for (int rg = 0; rg < 4; ++rg)
          ep[(prow + rg) * 17 + mrow] = acc[ms][ns][rg];
      }
      #pragma unroll
      for (int oo = 0; oo < 16; ++oo) {
        int o = oo0 + ns * 16 + oo;            // wave-uniform
        float v = ep[lane * 17 + oo];
        v = fmaf(v, scale_bo[b * COUT + o], nz + bias[o]);
        v = v > 0.f ? v : 0.2f * v;
        out[(((size_t)b * COUT + o) * H_ + h) * W_ + lane] = v;
      }
    }
  }
}

// =================== fallback fp32 direct conv (round-1, verified) ================
__global__ __launch_bounds__(256) void style_kernel(
    const float* __restrict__ w, const float* __restrict__ style_w,
    const float* __restrict__ style_b, float* __restrict__ style) {
  int gw = blockIdx.x * 4 + (threadIdx.x >> 6);
  int lane = threadIdx.x & 63;
  int b = gw >> 9, c = gw & 511;
  const float* wp = w + b * DLAT;
  const float* sw = style_w + c * DLAT;
  float v = 0.f;
  for (int d = lane; d < DLAT; d += 64) v = fmaf(wp[d], sw[d], v);
  #pragma unroll
  for (int off = 32; off > 0; off >>= 1) v += __shfl_down(v, off, 64);
  if (lane == 0) style[b * CIN + c] = fmaf(v, LIN_COEF, style_b[c]);
}
__global__ __launch_bounds__(256) void wsq_kernel(
    const float* __restrict__ conv_w, float* __restrict__ wsq) {
  int idx = blockIdx.x * 256 + threadIdx.x;
  const float* p = conv_w + (size_t)idx * 9;
  float s = 0.f;
  #pragma unroll
  for (int t = 0; t < 9; ++t) s = fmaf(p[t], p[t], s);
  wsq[idx] = s;
}
__global__ __launch_bounds__(256) void scale_kernel(
    const float* __restrict__ style, const float* __restrict__ wsq,
    float* __restrict__ scale_bo) {
  int gw = blockIdx.x * 4 + (threadIdx.x >> 6);
  int lane = threadIdx.x & 63;
  int b = gw >> 9, o = gw & 511;
  const float* st = style + b * CIN;
  const float* wq = wsq + o * CIN;
  float v = 0.f;
  for (int i = lane; i < CIN; i += 64) { float s = st[i]; v = fmaf(s * s, wq[i], v); }
  #pragma unroll
  for (int off = 32; off > 0; off >>= 1) v += __shfl_down(v, off, 64);
  if (lane == 0)
    scale_bo[b * COUT + o] = CONV_COEF * rsqrtf(fmaf(CONV_COEF * CONV_COEF, v, 1e-8f));
}
#define OTILE 32
#define HTILE 8
#define ICCH  8
#define XSTR  67
#define XROWS 10
__global__ __launch_bounds__(256) void conv_kernel(
    const float* __restrict__ x, const float* __restrict__ style,
    const float* __restrict__ conv_w, const float* __restrict__ scale_bo,
    const float* __restrict__ noise, const float* __restrict__ scale_noise,
    const float* __restrict__ bias, float* __restrict__ out) {
  __shared__ float xtile[ICCH * XROWS * XSTR];
  __shared__ float wt[OTILE * 72];
  const int tid = threadIdx.x;
  const int b = blockIdx.z, o0 = blockIdx.y * OTILE, h0 = blockIdx.x * HTILE;
  const int lane = tid & 63, oq = tid >> 6;
  const int r = lane >> 3, cg = lane & 7;
  float acc[8][8];
  #pragma unroll
  for (int a = 0; a < 8; ++a)
    #pragma unroll
    for (int c = 0; c < 8; ++c) acc[a][c] = 0.f;
  for (int ic0 = 0; ic0 < CIN; ic0 += ICCH) {
    for (int j = tid; j < ICCH * XROWS * XSTR; j += 256) {
      int i = j / (XROWS * XSTR);
      int rem = j - i * (XROWS * XSTR);
      int rr = rem / XSTR, cl = rem - rr * XSTR;
      if (cl < 66) {
        int hh = h0 - 1 + rr, wc = cl - 1;
        float v = 0.f;
        if ((unsigned)hh < 64u && (unsigned)wc < 64u)
          v = x[((size_t)(b * CIN + ic0 + i) * H_ + hh) * W_ + wc] * style[b * CIN + ic0 + i];
        xtile[j] = v;
      }
    }
    for (int j = tid; j < OTILE * 72; j += 256) {
      int oo = j / 72, q = j - oo * 72;
      wt[j] = conv_w[(size_t)(o0 + oo) * (CIN * 9) + ic0 * 9 + q];
    }
    __syncthreads();
    #pragma unroll 1
    for (int i = 0; i < ICCH; ++i) {
      const float* xbi = &xtile[i * (XROWS * XSTR) + r * XSTR + cg * 8];
      const float* wbi = &wt[oq * 8 * 72 + i * 9];
      #pragma unroll
      for (int ky = 0; ky < 3; ++ky) {
        float xr[10];
        #pragma unroll
        for (int q = 0; q < 10; ++q) xr[q] = xbi[ky * XSTR + q];
        #pragma unroll
        for (int kx = 0; kx < 3; ++kx) {
          #pragma unroll
          for (int oo = 0; oo < 8; ++oo) {
            float wv = wbi[oo * 72 + ky * 3 + kx];
            #pragma unroll
            for (int c = 0; c < 8; ++c) acc[oo][c] = fmaf(xr[c + kx], wv, acc[oo][c]);
          }
        }
      }
    }
    __syncthreads();
  }
  const float sn = scale_noise[0];
  const int row = h0 + r;
  float nz[8];
  #pragma unroll
  for (int c = 0; c < 8; ++c)
    nz[c] = sn * noise[((size_t)b * H_ + row) * W_ + cg * 8 + c];
  #pragma unroll
  for (int oo = 0; oo < 8; ++oo) {
    int o = o0 + oq * 8 + oo;
    float s = scale_bo[b * COUT + o];
    float bv = bias[o];
    float* op = out + ((size_t)(b * COUT + o) * H_ + row) * W_ + cg * 8;
    #pragma unroll
    for (int c = 0; c < 8; ++c) {
      float v = fmaf(acc[oo][c], s, nz[c] + bv);
      op[c] = v > 0.f ? v : 0.2f * v;
    }
  }
}

// ================================ launch ==========================================
extern "C" void kernel_launch(void* const* d_in, const int* in_sizes, int n_in,
                              void* d_out, int out_size, void* d_ws, size_t ws_size,
                              hipStream_t stream) {
  const float* x           = (const float*)d_in[0];
  const float* w           = (const float*)d_in[1];
  const float* noise       = (const float*)d_in[2];
  const float* style_w     = (const float*)d_in[3];
  const float* style_b     = (const float*)d_in[4];
  const float* conv_w      = (const float*)d_in[5];
  const float* scale_noise = (const float*)d_in[6];
  const float* bias        = (const float*)d_in[7];
  float* out = (float*)d_out;

  float* wsf      = (float*)d_ws;
  float* style    = wsf;            // 8192 f
  float* scale_bo = wsf + 8192;     // 8192 f
  float* wsq      = wsf + 16384;    // 262144 f -> ends at byte 1114112
  const size_t WTP_OFF = 1114112;
  const size_t XT_OFF  = WTP_OFF + (size_t)COUT * 9 * CIN * 2;      // +4718592
  const size_t NEED    = XT_OFF + (size_t)B_ * 66 * 66 * CIN * 2;   // 77201408

  if (ws_size >= NEED) {
    __hip_bfloat16* wtp2 = (__hip_bfloat16*)((char*)d_ws + WTP_OFF);
    __hip_bfloat16* xtp  = (__hip_bfloat16*)((char*)d_ws + XT_OFF);
    pre1<<<3072, 256, 0, stream>>>(w, style_w, style_b, conv_w, style, wsq);
    pre2<<<10816, 256, 0, stream>>>(x, style, wsq, conv_w, scale_bo, wtp2, xtp);
    dim3 grid(128, 4, 1);
    conv_mfma<<<grid, 512, 0, stream>>>(xtp, wtp2, scale_bo, noise,
                                        scale_noise, bias, out);
  } else {
    style_kernel<<<2048, 256, 0, stream>>>(w, style_w, style_b, style);
    wsq_kernel<<<1024, 256, 0, stream>>>(conv_w, wsq);
    scale_kernel<<<2048, 256, 0, stream>>>(style, wsq, scale_bo);
    dim3 grid(H_ / HTILE, COUT / OTILE, B_);
    conv_kernel<<<grid, 256, 0, stream>>>(x, style, conv_w, scale_bo,
                                          noise, scale_noise, bias, out);
  }
}

// Round 7
// 682.720 us; speedup vs baseline: 1.0785x; 1.0785x over previous
//
#include <hip/hip_runtime.h>
#include <hip/hip_bf16.h>

// StyleBlock: B=16, C_IN=512, C_OUT=512, D_LATENT=512, H=W=64, K=3
// R4 (verified, 270us, MfmaUtil 52%): 8-wave 512-thr, A burst-staged in LDS
// (XOR-swizzled, 2 barriers/chunk), B direct-global (L1-cached).
// R5 (B into LDS): 296us REGRESSION (exposed drain tripled). Reverted.
// R6 (A-prefetch, 1 barrier): 510us CATASTROPHE — in-order vmcnt forced the
// prefetch INTO each chunk's critical path, and de-synchronized staging killed
// L2 locality (FETCH 5x). Reverted.
// R7 (this round): exact R4 template + two parameter changes:
//   (a) BK=64: stage 2x42KB halves per burst (84480 B LDS) -> 8 drains not 16;
//   (b) XCD-chunked bijective swizzle (512=8*64), o-quarter fastest: the 4
//       blocks sharing an xt slice run concurrently on the SAME XCD -> staging
//       hits L2 not L3.

#define B_    16
#define CIN   512
#define COUT  512
#define DLAT  512
#define H_    64
#define W_    64

#define ABUF  42240            // 10 rows * 66 px * 4 granules * 16B
#define LDS_BYTES (2 * ABUF)   // two ic-halves per 64-ic burst

constexpr float LIN_COEF  = 0.04419417382415922f;   // 1/sqrt(512)
constexpr float CONV_COEF = 0.014731391274719739f;  // 1/sqrt(512*9)

typedef __attribute__((ext_vector_type(8))) short short8;
typedef __attribute__((ext_vector_type(4))) float f32x4;

__device__ __forceinline__ void gl2lds16(const void* g, void* l) {
  __builtin_amdgcn_global_load_lds(
      (const __attribute__((address_space(1))) unsigned*)g,
      (__attribute__((address_space(3))) unsigned*)l, 16, 0, 0);
}

// =============== pre-kernel 1: style | wsq  (3072 blocks) =========================
__global__ __launch_bounds__(256) void pre1(
    const float* __restrict__ w, const float* __restrict__ style_w,
    const float* __restrict__ style_b, const float* __restrict__ conv_w,
    float* __restrict__ style, float* __restrict__ wsq) {
  const int bid = blockIdx.x, tid = threadIdx.x;
  if (bid < 2048) {            // ---- style[b,c] ----
    int gw = bid * 4 + (tid >> 6), lane = tid & 63;
    int b = gw >> 9, c = gw & 511;
    const float* wp = w + b * DLAT;
    const float* sw = style_w + c * DLAT;
    float v = 0.f;
    for (int d = lane; d < DLAT; d += 64) v = fmaf(wp[d], sw[d], v);
    #pragma unroll
    for (int off = 32; off > 0; off >>= 1) v += __shfl_down(v, off, 64);
    if (lane == 0) style[b * CIN + c] = fmaf(v, LIN_COEF, style_b[c]);
  } else {                     // ---- wsq[o,i] ----
    int idx = (bid - 2048) * 256 + tid;
    const float* p = conv_w + (size_t)idx * 9;
    float s = 0.f;
    #pragma unroll
    for (int t = 0; t < 9; ++t) s = fmaf(p[t], p[t], s);
    wsq[idx] = s;
  }
}

// ====== pre-kernel 2: scale_bo | wtp2 | border-zero | xmod  (10816 blocks) ========
#define LSTR 136
__global__ __launch_bounds__(256) void pre2(
    const float* __restrict__ x, const float* __restrict__ style,
    const float* __restrict__ wsq, const float* __restrict__ conv_w,
    float* __restrict__ scale_bo, __hip_bfloat16* __restrict__ wtp2,
    __hip_bfloat16* __restrict__ xt) {
  __shared__ __align__(16) char sm2[18432];
  const int bid = blockIdx.x, tid = threadIdx.x;
  if (bid < 2048) {            // ---- scale_bo[b,o] ----
    int gw = bid * 4 + (tid >> 6), lane = tid & 63;
    int b = gw >> 9, o = gw & 511;
    const float* st = style + b * CIN;
    const float* wq = wsq + o * CIN;
    float v = 0.f;
    for (int i = lane; i < CIN; i += 64) { float s = st[i]; v = fmaf(s * s, wq[i], v); }
    #pragma unroll
    for (int off = 32; off > 0; off >>= 1) v += __shfl_down(v, off, 64);
    if (lane == 0)
      scale_bo[b * COUT + o] = CONV_COEF * rsqrtf(fmaf(CONV_COEF * CONV_COEF, v, 1e-8f));
  } else if (bid < 2560) {     // ---- wtp2[chunk][pos][kq][o][8] bf16 ----
    int o = bid - 2048;
    float* lw = (float*)sm2;
    for (int j = tid; j < CIN * 9; j += 256) lw[j] = conv_w[(size_t)o * (CIN * 9) + j];
    __syncthreads();
    for (int g = tid; g < 576; g += 256) {   // 16 chunks * 9 pos * 4 kq
      int chunk = g / 36, rem = g - chunk * 36, pos = rem >> 2, kqq = rem & 3;
      short8 v;
      #pragma unroll
      for (int e = 0; e < 8; ++e) {
        int ic = chunk * 32 + kqq * 8 + e;
        ((__hip_bfloat16*)&v)[e] = __float2bfloat16(lw[ic * 9 + pos]);
      }
      ((short8*)wtp2)[(size_t)g * 512 + o] = v;
    }
  } else if (bid < 6720) {     // ---- zero x_t halo border ----
    int idx = bid - 2560;      // 16*260
    int b = idx / 260, pb = idx - b * 260;
    int hh, ww;
    if (pb < 66)       { hh = 0;  ww = pb; }
    else if (pb < 132) { hh = 65; ww = pb - 66; }
    else if (pb < 196) { hh = pb - 132 + 1; ww = 0; }
    else               { hh = pb - 196 + 1; ww = 65; }
    unsigned* p = (unsigned*)(xt + (((size_t)b * 66 + hh) * 66 + ww) * CIN);
    p[tid] = 0u;
  } else {                     // ---- x_t[b][h+1][w+1][ic] = bf16(x * style) ----
    int idx = bid - 6720;      // 16*64*4
    int b = idx >> 8, rem = idx & 255, h = rem >> 2, ic0 = (rem & 3) * 128;
    __hip_bfloat16* ls = (__hip_bfloat16*)sm2;      // [64 w][LSTR ic]
    for (int j = tid; j < 2048; j += 256) {         // 128 ic x 16 w-quads
      int i = j >> 4, wq = j & 15;
      const float4 xv = *(const float4*)&x[(((size_t)b * CIN + ic0 + i) * H_ + h) * W_ + wq * 4];
      float st = style[b * CIN + ic0 + i];
      ls[(wq * 4 + 0) * LSTR + i] = __float2bfloat16(xv.x * st);
      ls[(wq * 4 + 1) * LSTR + i] = __float2bfloat16(xv.y * st);
      ls[(wq * 4 + 2) * LSTR + i] = __float2bfloat16(xv.z * st);
      ls[(wq * 4 + 3) * LSTR + i] = __float2bfloat16(xv.w * st);
    }
    __syncthreads();
    for (int j = tid; j < 1024; j += 256) {
      int ww = j >> 4, part = j & 15;
      __hip_bfloat16* dst = xt + (((size_t)b * 66 + h + 1) * 66 + (ww + 1)) * CIN + ic0 + part * 8;
      *(short8*)dst = *(const short8*)(ls + ww * LSTR + part * 8);
    }
  }
}

// ========== main conv: block = 8 rows x 64 px x 128 o, 8 waves (512 thr) ==========
// Wave (wr=wv>>1, wc=wv&1): rows h0+wr*2..+1, o-half wc. Per-wave tile 128px x 64o
// = 8x4 MFMA 16x16x32 frags, acc 128 VGPR. B direct-global (L1-cached).
// LDS: per 64-ic burst, TWO 42240-B A-halves staged between the same verified
// 2-barrier pattern (8 bursts instead of 16). XOR swizzle unchanged.
// Grid: 1-D 512 blocks, XCD-chunked bijective swizzle, o-quarter fastest.
__global__ __launch_bounds__(512, 2) void conv_mfma(
    const __hip_bfloat16* __restrict__ xt, const __hip_bfloat16* __restrict__ wtp2,
    const float* __restrict__ scale_bo, const float* __restrict__ noise,
    const float* __restrict__ scale_noise, const float* __restrict__ bias,
    float* __restrict__ out) {
  __shared__ __align__(16) char smem[LDS_BYTES];

  const int tid = threadIdx.x, lane = tid & 63, wv = tid >> 6;
  const int mrow = lane & 15, kq = lane >> 4;
  const int wr = wv >> 1, wc = wv & 1;

  // XCD-chunked swizzle: 512 blocks = 8 XCDs x 64. Within a chunk, o-quarter
  // varies fastest so the 4 blocks sharing an xt slice are co-resident on one XCD.
  const int bid = blockIdx.x;
  const int wg  = (bid & 7) * 64 + (bid >> 3);   // bijective remap
  const int oq  = wg & 3;                        // o-quarter (fastest)
  const int sp  = wg >> 2;                       // spatial tile 0..127
  const int b   = sp >> 3;
  const int h0  = (sp & 7) << 3;                 // 8 output rows per block
  const int oo0 = (oq << 7) + (wc << 6);
  const int r0  = h0 + (wr << 1);                // wave's first output row

  // ---- A staging: granule t = wv*330 + i*64 + lane; pixel p=t>>2, slot s=t&3,
  //      holds ic-group q = s ^ ((p>>1)&3)  (XOR bank swizzle) ----
  const size_t xbase = ((size_t)(b * 66 + h0)) * (66 * 512);
  int xoff[6];
  #pragma unroll
  for (int i = 0; i < 6; ++i) {
    int r = i * 64 + lane;                   // within-wave granule rank
    if (r < 330) {
      int t = wv * 330 + r;
      int p = t >> 2, s = t & 3;
      int q = s ^ ((p >> 1) & 3);
      xoff[i] = p * 512 + q * 8;
    } else xoff[i] = -1;
  }
  const int ldst = wv * 5280;                // (wv*330)*16

  f32x4 acc[8][4] = {};        // [ms][ns]
  int pbase[8];
  #pragma unroll
  for (int ms = 0; ms < 8; ++ms)
    pbase[ms] = ((wr << 1) + (ms >> 2)) * 66 + (ms & 3) * 16 + mrow;

  const short8* bbase = (const short8*)wtp2 + (kq * 512 + oo0 + mrow);

  for (int cc = 0; cc < 8; ++cc) {           // 8 bursts of 64 ic
    const int ic0 = cc << 6;
    __syncthreads();                         // LDS free
    #pragma unroll
    for (int i = 0; i < 6; ++i)
      if (xoff[i] >= 0) {
        gl2lds16(xt + xbase + xoff[i] + ic0,      smem + ldst + i * 1024);
        gl2lds16(xt + xbase + xoff[i] + ic0 + 32, smem + ABUF + ldst + i * 1024);
      }
    __syncthreads();                         // burst ready (full drain)

    #pragma unroll
    for (int sub = 0; sub < 2; ++sub) {
      const char* abuf = smem + sub * ABUF;
      const int ch9 = (cc * 2 + sub) * 9;
      #pragma unroll
      for (int ky = 0; ky < 3; ++ky) {
        #pragma unroll
        for (int kx = 0; kx < 3; ++kx) {
          const short8* bp = bbase + (size_t)(ch9 + ky * 3 + kx) * 2048;
          short8 bf0 = bp[0], bf1 = bp[16], bf2 = bp[32], bf3 = bp[48];
          short8 af[8];
          #pragma unroll
          for (int ms = 0; ms < 8; ++ms) {
            int p = pbase[ms] + ky * 66 + kx;
            int s = kq ^ ((p >> 1) & 3);
            af[ms] = *(const short8*)(abuf + p * 64 + s * 16);
          }
          #pragma unroll
          for (int ms = 0; ms < 8; ++ms) {
            acc[ms][0] = __builtin_amdgcn_mfma_f32_16x16x32_bf16(af[ms], bf0, acc[ms][0], 0, 0, 0);
            acc[ms][1] = __builtin_amdgcn_mfma_f32_16x16x32_bf16(af[ms], bf1, acc[ms][1], 0, 0, 0);
            acc[ms][2] = __builtin_amdgcn_mfma_f32_16x16x32_bf16(af[ms], bf2, acc[ms][2], 0, 0, 0);
            acc[ms][3] = __builtin_amdgcn_mfma_f32_16x16x32_bf16(af[ms], bf3, acc[ms][3], 0, 0, 0);
          }
        }
      }
    }
  }

  // ---- epilogue: per-wave LDS transpose -> coalesced stores ----
  __syncthreads();                             // all frag reads done
  float* ep = (float*)smem + wv * 1088;        // 64 x 17 f32 per wave (private)
  const float sn = scale_noise[0];

  #pragma unroll
  for (int r = 0; r < 2; ++r) {
    const int h = r0 + r;
    const float nz = sn * noise[((size_t)b * H_ + h) * W_ + lane];
    for (int ns = 0; ns < 4; ++ns) {
      #pragma unroll
      for (int m4 = 0; m4 < 4; ++m4) {
        int ms = r * 4 + m4;
        int prow = m4 * 16 + kq * 4;           // pixel col within row
        #pragma unroll
        for (int rg = 0; rg < 4; ++rg)
          ep[(prow + rg) * 17 + mrow] = acc[ms][ns][rg];
      }
      #pragma unroll
      for (int oo = 0; oo < 16; ++oo) {
        int o = oo0 + ns * 16 + oo;            // wave-uniform
        float v = ep[lane * 17 + oo];
        v = fmaf(v, scale_bo[b * COUT + o], nz + bias[o]);
        v = v > 0.f ? v : 0.2f * v;
        out[(((size_t)b * COUT + o) * H_ + h) * W_ + lane] = v;
      }
    }
  }
}

// =================== fallback fp32 direct conv (round-1, verified) ================
__global__ __launch_bounds__(256) void style_kernel(
    const float* __restrict__ w, const float* __restrict__ style_w,
    const float* __restrict__ style_b, float* __restrict__ style) {
  int gw = blockIdx.x * 4 + (threadIdx.x >> 6);
  int lane = threadIdx.x & 63;
  int b = gw >> 9, c = gw & 511;
  const float* wp = w + b * DLAT;
  const float* sw = style_w + c * DLAT;
  float v = 0.f;
  for (int d = lane; d < DLAT; d += 64) v = fmaf(wp[d], sw[d], v);
  #pragma unroll
  for (int off = 32; off > 0; off >>= 1) v += __shfl_down(v, off, 64);
  if (lane == 0) style[b * CIN + c] = fmaf(v, LIN_COEF, style_b[c]);
}
__global__ __launch_bounds__(256) void wsq_kernel(
    const float* __restrict__ conv_w, float* __restrict__ wsq) {
  int idx = blockIdx.x * 256 + threadIdx.x;
  const float* p = conv_w + (size_t)idx * 9;
  float s = 0.f;
  #pragma unroll
  for (int t = 0; t < 9; ++t) s = fmaf(p[t], p[t], s);
  wsq[idx] = s;
}
__global__ __launch_bounds__(256) void scale_kernel(
    const float* __restrict__ style, const float* __restrict__ wsq,
    float* __restrict__ scale_bo) {
  int gw = blockIdx.x * 4 + (threadIdx.x >> 6);
  int lane = threadIdx.x & 63;
  int b = gw >> 9, o = gw & 511;
  const float* st = style + b * CIN;
  const float* wq = wsq + o * CIN;
  float v = 0.f;
  for (int i = lane; i < CIN; i += 64) { float s = st[i]; v = fmaf(s * s, wq[i], v); }
  #pragma unroll
  for (int off = 32; off > 0; off >>= 1) v += __shfl_down(v, off, 64);
  if (lane == 0)
    scale_bo[b * COUT + o] = CONV_COEF * rsqrtf(fmaf(CONV_COEF * CONV_COEF, v, 1e-8f));
}
#define OTILE 32
#define HTILE 8
#define ICCH  8
#define XSTR  67
#define XROWS 10
__global__ __launch_bounds__(256) void conv_kernel(
    const float* __restrict__ x, const float* __restrict__ style,
    const float* __restrict__ conv_w, const float* __restrict__ scale_bo,
    const float* __restrict__ noise, const float* __restrict__ scale_noise,
    const float* __restrict__ bias, float* __restrict__ out) {
  __shared__ float xtile[ICCH * XROWS * XSTR];
  __shared__ float wt[OTILE * 72];
  const int tid = threadIdx.x;
  const int b = blockIdx.z, o0 = blockIdx.y * OTILE, h0 = blockIdx.x * HTILE;
  const int lane = tid & 63, oq = tid >> 6;
  const int r = lane >> 3, cg = lane & 7;
  float acc[8][8];
  #pragma unroll
  for (int a = 0; a < 8; ++a)
    #pragma unroll
    for (int c = 0; c < 8; ++c) acc[a][c] = 0.f;
  for (int ic0 = 0; ic0 < CIN; ic0 += ICCH) {
    for (int j = tid; j < ICCH * XROWS * XSTR; j += 256) {
      int i = j / (XROWS * XSTR);
      int rem = j - i * (XROWS * XSTR);
      int rr = rem / XSTR, cl = rem - rr * XSTR;
      if (cl < 66) {
        int hh = h0 - 1 + rr, wc = cl - 1;
        float v = 0.f;
        if ((unsigned)hh < 64u && (unsigned)wc < 64u)
          v = x[((size_t)(b * CIN + ic0 + i) * H_ + hh) * W_ + wc] * style[b * CIN + ic0 + i];
        xtile[j] = v;
      }
    }
    for (int j = tid; j < OTILE * 72; j += 256) {
      int oo = j / 72, q = j - oo * 72;
      wt[j] = conv_w[(size_t)(o0 + oo) * (CIN * 9) + ic0 * 9 + q];
    }
    __syncthreads();
    #pragma unroll 1
    for (int i = 0; i < ICCH; ++i) {
      const float* xbi = &xtile[i * (XROWS * XSTR) + r * XSTR + cg * 8];
      const float* wbi = &wt[oq * 8 * 72 + i * 9];
      #pragma unroll
      for (int ky = 0; ky < 3; ++ky) {
        float xr[10];
        #pragma unroll
        for (int q = 0; q < 10; ++q) xr[q] = xbi[ky * XSTR + q];
        #pragma unroll
        for (int kx = 0; kx < 3; ++kx) {
          #pragma unroll
          for (int oo = 0; oo < 8; ++oo) {
            float wv = wbi[oo * 72 + ky * 3 + kx];
            #pragma unroll
            for (int c = 0; c < 8; ++c) acc[oo][c] = fmaf(xr[c + kx], wv, acc[oo][c]);
          }
        }
      }
    }
    __syncthreads();
  }
  const float sn = scale_noise[0];
  const int row = h0 + r;
  float nz[8];
  #pragma unroll
  for (int c = 0; c < 8; ++c)
    nz[c] = sn * noise[((size_t)b * H_ + row) * W_ + cg * 8 + c];
  #pragma unroll
  for (int oo = 0; oo < 8; ++oo) {
    int o = o0 + oq * 8 + oo;
    float s = scale_bo[b * COUT + o];
    float bv = bias[o];
    float* op = out + ((size_t)(b * COUT + o) * H_ + row) * W_ + cg * 8;
    #pragma unroll
    for (int c = 0; c < 8; ++c) {
      float v = fmaf(acc[oo][c], s, nz[c] + bv);
      op[c] = v > 0.f ? v : 0.2f * v;
    }
  }
}

// ================================ launch ==========================================
extern "C" void kernel_launch(void* const* d_in, const int* in_sizes, int n_in,
                              void* d_out, int out_size, void* d_ws, size_t ws_size,
                              hipStream_t stream) {
  const float* x           = (const float*)d_in[0];
  const float* w           = (const float*)d_in[1];
  const float* noise       = (const float*)d_in[2];
  const float* style_w     = (const float*)d_in[3];
  const float* style_b     = (const float*)d_in[4];
  const float* conv_w      = (const float*)d_in[5];
  const float* scale_noise = (const float*)d_in[6];
  const float* bias        = (const float*)d_in[7];
  float* out = (float*)d_out;

  float* wsf      = (float*)d_ws;
  float* style    = wsf;            // 8192 f
  float* scale_bo = wsf + 8192;     // 8192 f
  float* wsq      = wsf + 16384;    // 262144 f -> ends at byte 1114112
  const size_t WTP_OFF = 1114112;
  const size_t XT_OFF  = WTP_OFF + (size_t)COUT * 9 * CIN * 2;      // +4718592
  const size_t NEED    = XT_OFF + (size_t)B_ * 66 * 66 * CIN * 2;   // 77201408

  if (ws_size >= NEED) {
    __hip_bfloat16* wtp2 = (__hip_bfloat16*)((char*)d_ws + WTP_OFF);
    __hip_bfloat16* xtp  = (__hip_bfloat16*)((char*)d_ws + XT_OFF);
    pre1<<<3072, 256, 0, stream>>>(w, style_w, style_b, conv_w, style, wsq);
    pre2<<<10816, 256, 0, stream>>>(x, style, wsq, conv_w, scale_bo, wtp2, xtp);
    conv_mfma<<<512, 512, 0, stream>>>(xtp, wtp2, scale_bo, noise,
                                       scale_noise, bias, out);
  } else {
    style_kernel<<<2048, 256, 0, stream>>>(w, style_w, style_b, style);
    wsq_kernel<<<1024, 256, 0, stream>>>(conv_w, wsq);
    scale_kernel<<<2048, 256, 0, stream>>>(style, wsq, scale_bo);
    dim3 grid(H_ / HTILE, COUT / OTILE, B_);
    conv_kernel<<<grid, 256, 0, stream>>>(x, style, conv_w, scale_bo,
                                          noise, scale_noise, bias, out);
  }
}

// Round 8
// 493.541 us; speedup vs baseline: 1.4919x; 1.3833x over previous
//
#include <hip/hip_runtime.h>
#include <hip/hip_bf16.h>

// StyleBlock: B=16, C_IN=512, C_OUT=512, D_LATENT=512, H=W=64, K=3
// VERIFIED BEST (R4): 8-wave 512-thr conv_mfma, A burst-staged in LDS
// (XOR-swizzled, 2 barriers per 32-ic chunk), B direct-global (L1-cached),
// 2-D grid(128,4). 270us conv / 496us total, MfmaUtil 52%, FETCH 107MB.
// FAILED departures (do not retry without new evidence):
//   R5  B into LDS:            296us (exposed drain tripled, LDS pipe sat.)
//   R6  A dbuf + 1 barrier:    510us (in-order vmcnt put prefetch on crit path;
//                                     FETCH 5x)
//   R7  BK=64 + XCD swizzle:   470us (FETCH 4.3x — locality model contradicted;
//                                     default 2-D grid already co-locates
//                                     o-siblings per XCD: x+128k = x mod 8)
// R8 (this round): exact R4 revert — recover best-known, fresh counters.

#define B_    16
#define CIN   512
#define COUT  512
#define DLAT  512
#define H_    64
#define W_    64

constexpr float LIN_COEF  = 0.04419417382415922f;   // 1/sqrt(512)
constexpr float CONV_COEF = 0.014731391274719739f;  // 1/sqrt(512*9)

typedef __attribute__((ext_vector_type(8))) short short8;
typedef __attribute__((ext_vector_type(4))) float f32x4;

__device__ __forceinline__ void gl2lds16(const void* g, void* l) {
  __builtin_amdgcn_global_load_lds(
      (const __attribute__((address_space(1))) unsigned*)g,
      (__attribute__((address_space(3))) unsigned*)l, 16, 0, 0);
}

// =============== pre-kernel 1: style | wsq  (3072 blocks) =========================
__global__ __launch_bounds__(256) void pre1(
    const float* __restrict__ w, const float* __restrict__ style_w,
    const float* __restrict__ style_b, const float* __restrict__ conv_w,
    float* __restrict__ style, float* __restrict__ wsq) {
  const int bid = blockIdx.x, tid = threadIdx.x;
  if (bid < 2048) {            // ---- style[b,c] ----
    int gw = bid * 4 + (tid >> 6), lane = tid & 63;
    int b = gw >> 9, c = gw & 511;
    const float* wp = w + b * DLAT;
    const float* sw = style_w + c * DLAT;
    float v = 0.f;
    for (int d = lane; d < DLAT; d += 64) v = fmaf(wp[d], sw[d], v);
    #pragma unroll
    for (int off = 32; off > 0; off >>= 1) v += __shfl_down(v, off, 64);
    if (lane == 0) style[b * CIN + c] = fmaf(v, LIN_COEF, style_b[c]);
  } else {                     // ---- wsq[o,i] ----
    int idx = (bid - 2048) * 256 + tid;
    const float* p = conv_w + (size_t)idx * 9;
    float s = 0.f;
    #pragma unroll
    for (int t = 0; t < 9; ++t) s = fmaf(p[t], p[t], s);
    wsq[idx] = s;
  }
}

// ====== pre-kernel 2: scale_bo | wtp2 | border-zero | xmod  (10816 blocks) ========
#define LSTR 136
__global__ __launch_bounds__(256) void pre2(
    const float* __restrict__ x, const float* __restrict__ style,
    const float* __restrict__ wsq, const float* __restrict__ conv_w,
    float* __restrict__ scale_bo, __hip_bfloat16* __restrict__ wtp2,
    __hip_bfloat16* __restrict__ xt) {
  __shared__ __align__(16) char sm2[18432];
  const int bid = blockIdx.x, tid = threadIdx.x;
  if (bid < 2048) {            // ---- scale_bo[b,o] ----
    int gw = bid * 4 + (tid >> 6), lane = tid & 63;
    int b = gw >> 9, o = gw & 511;
    const float* st = style + b * CIN;
    const float* wq = wsq + o * CIN;
    float v = 0.f;
    for (int i = lane; i < CIN; i += 64) { float s = st[i]; v = fmaf(s * s, wq[i], v); }
    #pragma unroll
    for (int off = 32; off > 0; off >>= 1) v += __shfl_down(v, off, 64);
    if (lane == 0)
      scale_bo[b * COUT + o] = CONV_COEF * rsqrtf(fmaf(CONV_COEF * CONV_COEF, v, 1e-8f));
  } else if (bid < 2560) {     // ---- wtp2[chunk][pos][kq][o][8] bf16 ----
    int o = bid - 2048;
    float* lw = (float*)sm2;
    for (int j = tid; j < CIN * 9; j += 256) lw[j] = conv_w[(size_t)o * (CIN * 9) + j];
    __syncthreads();
    for (int g = tid; g < 576; g += 256) {   // 16 chunks * 9 pos * 4 kq
      int chunk = g / 36, rem = g - chunk * 36, pos = rem >> 2, kqq = rem & 3;
      short8 v;
      #pragma unroll
      for (int e = 0; e < 8; ++e) {
        int ic = chunk * 32 + kqq * 8 + e;
        ((__hip_bfloat16*)&v)[e] = __float2bfloat16(lw[ic * 9 + pos]);
      }
      ((short8*)wtp2)[(size_t)g * 512 + o] = v;
    }
  } else if (bid < 6720) {     // ---- zero x_t halo border ----
    int idx = bid - 2560;      // 16*260
    int b = idx / 260, pb = idx - b * 260;
    int hh, ww;
    if (pb < 66)       { hh = 0;  ww = pb; }
    else if (pb < 132) { hh = 65; ww = pb - 66; }
    else if (pb < 196) { hh = pb - 132 + 1; ww = 0; }
    else               { hh = pb - 196 + 1; ww = 65; }
    unsigned* p = (unsigned*)(xt + (((size_t)b * 66 + hh) * 66 + ww) * CIN);
    p[tid] = 0u;
  } else {                     // ---- x_t[b][h+1][w+1][ic] = bf16(x * style) ----
    int idx = bid - 6720;      // 16*64*4
    int b = idx >> 8, rem = idx & 255, h = rem >> 2, ic0 = (rem & 3) * 128;
    __hip_bfloat16* ls = (__hip_bfloat16*)sm2;      // [64 w][LSTR ic]
    for (int j = tid; j < 2048; j += 256) {         // 128 ic x 16 w-quads
      int i = j >> 4, wq = j & 15;
      const float4 xv = *(const float4*)&x[(((size_t)b * CIN + ic0 + i) * H_ + h) * W_ + wq * 4];
      float st = style[b * CIN + ic0 + i];
      ls[(wq * 4 + 0) * LSTR + i] = __float2bfloat16(xv.x * st);
      ls[(wq * 4 + 1) * LSTR + i] = __float2bfloat16(xv.y * st);
      ls[(wq * 4 + 2) * LSTR + i] = __float2bfloat16(xv.z * st);
      ls[(wq * 4 + 3) * LSTR + i] = __float2bfloat16(xv.w * st);
    }
    __syncthreads();
    for (int j = tid; j < 1024; j += 256) {
      int ww = j >> 4, part = j & 15;
      __hip_bfloat16* dst = xt + (((size_t)b * 66 + h + 1) * 66 + (ww + 1)) * CIN + ic0 + part * 8;
      *(short8*)dst = *(const short8*)(ls + ww * LSTR + part * 8);
    }
  }
}

// ========== main conv: block = 8 rows x 64 px x 128 o, 8 waves (512 thr) ==========
// Wave (wr=wv>>1, wc=wv&1): rows h0+wr*2..+1, o-half wc. Per-wave tile 128px x 64o
// = 8x4 MFMA 16x16x32 frags, acc 128 VGPR.
// LDS A-tile: 10 input rows x 66 px x 32 ic bf16, XOR-swizzled = 42240 B,
// staged by 8 waves x 330 granules (2640 = 8*330 exact).
__global__ __launch_bounds__(512, 2) void conv_mfma(
    const __hip_bfloat16* __restrict__ xt, const __hip_bfloat16* __restrict__ wtp2,
    const float* __restrict__ scale_bo, const float* __restrict__ noise,
    const float* __restrict__ scale_noise, const float* __restrict__ bias,
    float* __restrict__ out) {
  __shared__ __align__(16) char smem[42240];

  const int tid = threadIdx.x, lane = tid & 63, wv = tid >> 6;
  const int mrow = lane & 15, kq = lane >> 4;
  const int wr = wv >> 1, wc = wv & 1;
  const int b  = blockIdx.x >> 3;
  const int h0 = (blockIdx.x & 7) << 3;      // 8 output rows per block
  const int oo0 = (blockIdx.y << 7) + (wc << 6);
  const int r0 = h0 + (wr << 1);             // wave's first output row

  // ---- staging: granule t = wv*330 + i*64 + lane; pixel p=t>>2, slot s=t&3,
  //      holds ic-group q = s ^ ((p>>1)&3)  (XOR bank swizzle) ----
  const size_t xbase = ((size_t)(b * 66 + h0)) * (66 * 512);
  int xoff[6];
  #pragma unroll
  for (int i = 0; i < 6; ++i) {
    int r = i * 64 + lane;                   // within-wave granule rank
    if (r < 330) {
      int t = wv * 330 + r;
      int p = t >> 2, s = t & 3;
      int q = s ^ ((p >> 1) & 3);
      xoff[i] = p * 512 + q * 8;
    } else xoff[i] = -1;
  }

  f32x4 acc[8][4] = {};        // [ms][ns]
  int pbase[8];
  #pragma unroll
  for (int ms = 0; ms < 8; ++ms)
    pbase[ms] = ((wr << 1) + (ms >> 2)) * 66 + (ms & 3) * 16 + mrow;

  const short8* bbase = (const short8*)wtp2 + (kq * 512 + oo0 + mrow);

  for (int ic0 = 0; ic0 < CIN; ic0 += 32) {
    __syncthreads();                           // A-tile free
    #pragma unroll
    for (int i = 0; i < 6; ++i)
      if (xoff[i] >= 0)
        gl2lds16(xt + xbase + xoff[i] + ic0, smem + (wv * 330 + i * 64) * 16);
    __syncthreads();                           // A-tile ready (full drain)

    const int ch9 = (ic0 >> 5) * 9;
    #pragma unroll
    for (int ky = 0; ky < 3; ++ky) {
      #pragma unroll
      for (int kx = 0; kx < 3; ++kx) {
        const short8* bp = bbase + (size_t)(ch9 + ky * 3 + kx) * 2048;
        short8 bf0 = bp[0], bf1 = bp[16], bf2 = bp[32], bf3 = bp[48];
        short8 af[8];
        #pragma unroll
        for (int ms = 0; ms < 8; ++ms) {
          int p = pbase[ms] + ky * 66 + kx;
          int s = kq ^ ((p >> 1) & 3);
          af[ms] = *(const short8*)(smem + p * 64 + s * 16);
        }
        #pragma unroll
        for (int ms = 0; ms < 8; ++ms) {
          acc[ms][0] = __builtin_amdgcn_mfma_f32_16x16x32_bf16(af[ms], bf0, acc[ms][0], 0, 0, 0);
          acc[ms][1] = __builtin_amdgcn_mfma_f32_16x16x32_bf16(af[ms], bf1, acc[ms][1], 0, 0, 0);
          acc[ms][2] = __builtin_amdgcn_mfma_f32_16x16x32_bf16(af[ms], bf2, acc[ms][2], 0, 0, 0);
          acc[ms][3] = __builtin_amdgcn_mfma_f32_16x16x32_bf16(af[ms], bf3, acc[ms][3], 0, 0, 0);
        }
      }
    }
  }

  // ---- epilogue: per-wave LDS transpose -> coalesced stores ----
  __syncthreads();                             // all frag reads done
  float* ep = (float*)smem + wv * 1088;        // 64 x 17 f32 per wave (private)
  const float sn = scale_noise[0];

  #pragma unroll
  for (int r = 0; r < 2; ++r) {
    const int h = r0 + r;
    const float nz = sn * noise[((size_t)b * H_ + h) * W_ + lane];
    for (int ns = 0; ns < 4; ++ns) {
      #pragma unroll
      for (int m4 = 0; m4 < 4; ++m4) {
        int ms = r * 4 + m4;
        int prow = m4 * 16 + kq * 4;           // pixel col within row
        #pragma unroll
        for (int rg = 0; rg < 4; ++rg)
          ep[(prow + rg) * 17 + mrow] = acc[ms][ns][rg];
      }
      #pragma unroll
      for (int oo = 0; oo < 16; ++oo) {
        int o = oo0 + ns * 16 + oo;            // wave-uniform
        float v = ep[lane * 17 + oo];
        v = fmaf(v, scale_bo[b * COUT + o], nz + bias[o]);
        v = v > 0.f ? v : 0.2f * v;
        out[(((size_t)b * COUT + o) * H_ + h) * W_ + lane] = v;
      }
    }
  }
}

// =================== fallback fp32 direct conv (round-1, verified) ================
__global__ __launch_bounds__(256) void style_kernel(
    const float* __restrict__ w, const float* __restrict__ style_w,
    const float* __restrict__ style_b, float* __restrict__ style) {
  int gw = blockIdx.x * 4 + (threadIdx.x >> 6);
  int lane = threadIdx.x & 63;
  int b = gw >> 9, c = gw & 511;
  const float* wp = w + b * DLAT;
  const float* sw = style_w + c * DLAT;
  float v = 0.f;
  for (int d = lane; d < DLAT; d += 64) v = fmaf(wp[d], sw[d], v);
  #pragma unroll
  for (int off = 32; off > 0; off >>= 1) v += __shfl_down(v, off, 64);
  if (lane == 0) style[b * CIN + c] = fmaf(v, LIN_COEF, style_b[c]);
}
__global__ __launch_bounds__(256) void wsq_kernel(
    const float* __restrict__ conv_w, float* __restrict__ wsq) {
  int idx = blockIdx.x * 256 + threadIdx.x;
  const float* p = conv_w + (size_t)idx * 9;
  float s = 0.f;
  #pragma unroll
  for (int t = 0; t < 9; ++t) s = fmaf(p[t], p[t], s);
  wsq[idx] = s;
}
__global__ __launch_bounds__(256) void scale_kernel(
    const float* __restrict__ style, const float* __restrict__ wsq,
    float* __restrict__ scale_bo) {
  int gw = blockIdx.x * 4 + (threadIdx.x >> 6);
  int lane = threadIdx.x & 63;
  int b = gw >> 9, o = gw & 511;
  const float* st = style + b * CIN;
  const float* wq = wsq + o * CIN;
  float v = 0.f;
  for (int i = lane; i < CIN; i += 64) { float s = st[i]; v = fmaf(s * s, wq[i], v); }
  #pragma unroll
  for (int off = 32; off > 0; off >>= 1) v += __shfl_down(v, off, 64);
  if (lane == 0)
    scale_bo[b * COUT + o] = CONV_COEF * rsqrtf(fmaf(CONV_COEF * CONV_COEF, v, 1e-8f));
}
#define OTILE 32
#define HTILE 8
#define ICCH  8
#define XSTR  67
#define XROWS 10
__global__ __launch_bounds__(256) void conv_kernel(
    const float* __restrict__ x, const float* __restrict__ style,
    const float* __restrict__ conv_w, const float* __restrict__ scale_bo,
    const float* __restrict__ noise, const float* __restrict__ scale_noise,
    const float* __restrict__ bias, float* __restrict__ out) {
  __shared__ float xtile[ICCH * XROWS * XSTR];
  __shared__ float wt[OTILE * 72];
  const int tid = threadIdx.x;
  const int b = blockIdx.z, o0 = blockIdx.y * OTILE, h0 = blockIdx.x * HTILE;
  const int lane = tid & 63, oq = tid >> 6;
  const int r = lane >> 3, cg = lane & 7;
  float acc[8][8];
  #pragma unroll
  for (int a = 0; a < 8; ++a)
    #pragma unroll
    for (int c = 0; c < 8; ++c) acc[a][c] = 0.f;
  for (int ic0 = 0; ic0 < CIN; ic0 += ICCH) {
    for (int j = tid; j < ICCH * XROWS * XSTR; j += 256) {
      int i = j / (XROWS * XSTR);
      int rem = j - i * (XROWS * XSTR);
      int rr = rem / XSTR, cl = rem - rr * XSTR;
      if (cl < 66) {
        int hh = h0 - 1 + rr, wc = cl - 1;
        float v = 0.f;
        if ((unsigned)hh < 64u && (unsigned)wc < 64u)
          v = x[((size_t)(b * CIN + ic0 + i) * H_ + hh) * W_ + wc] * style[b * CIN + ic0 + i];
        xtile[j] = v;
      }
    }
    for (int j = tid; j < OTILE * 72; j += 256) {
      int oo = j / 72, q = j - oo * 72;
      wt[j] = conv_w[(size_t)(o0 + oo) * (CIN * 9) + ic0 * 9 + q];
    }
    __syncthreads();
    #pragma unroll 1
    for (int i = 0; i < ICCH; ++i) {
      const float* xbi = &xtile[i * (XROWS * XSTR) + r * XSTR + cg * 8];
      const float* wbi = &wt[oq * 8 * 72 + i * 9];
      #pragma unroll
      for (int ky = 0; ky < 3; ++ky) {
        float xr[10];
        #pragma unroll
        for (int q = 0; q < 10; ++q) xr[q] = xbi[ky * XSTR + q];
        #pragma unroll
        for (int kx = 0; kx < 3; ++kx) {
          #pragma unroll
          for (int oo = 0; oo < 8; ++oo) {
            float wv = wbi[oo * 72 + ky * 3 + kx];
            #pragma unroll
            for (int c = 0; c < 8; ++c) acc[oo][c] = fmaf(xr[c + kx], wv, acc[oo][c]);
          }
        }
      }
    }
    __syncthreads();
  }
  const float sn = scale_noise[0];
  const int row = h0 + r;
  float nz[8];
  #pragma unroll
  for (int c = 0; c < 8; ++c)
    nz[c] = sn * noise[((size_t)b * H_ + row) * W_ + cg * 8 + c];
  #pragma unroll
  for (int oo = 0; oo < 8; ++oo) {
    int o = o0 + oq * 8 + oo;
    float s = scale_bo[b * COUT + o];
    float bv = bias[o];
    float* op = out + ((size_t)(b * COUT + o) * H_ + row) * W_ + cg * 8;
    #pragma unroll
    for (int c = 0; c < 8; ++c) {
      float v = fmaf(acc[oo][c], s, nz[c] + bv);
      op[c] = v > 0.f ? v : 0.2f * v;
    }
  }
}

// ================================ launch ==========================================
extern "C" void kernel_launch(void* const* d_in, const int* in_sizes, int n_in,
                              void* d_out, int out_size, void* d_ws, size_t ws_size,
                              hipStream_t stream) {
  const float* x           = (const float*)d_in[0];
  const float* w           = (const float*)d_in[1];
  const float* noise       = (const float*)d_in[2];
  const float* style_w     = (const float*)d_in[3];
  const float* style_b     = (const float*)d_in[4];
  const float* conv_w      = (const float*)d_in[5];
  const float* scale_noise = (const float*)d_in[6];
  const float* bias        = (const float*)d_in[7];
  float* out = (float*)d_out;

  float* wsf      = (float*)d_ws;
  float* style    = wsf;            // 8192 f
  float* scale_bo = wsf + 8192;     // 8192 f
  float* wsq      = wsf + 16384;    // 262144 f -> ends at byte 1114112
  const size_t WTP_OFF = 1114112;
  const size_t XT_OFF  = WTP_OFF + (size_t)COUT * 9 * CIN * 2;      // +4718592
  const size_t NEED    = XT_OFF + (size_t)B_ * 66 * 66 * CIN * 2;   // 77201408

  if (ws_size >= NEED) {
    __hip_bfloat16* wtp2 = (__hip_bfloat16*)((char*)d_ws + WTP_OFF);
    __hip_bfloat16* xtp  = (__hip_bfloat16*)((char*)d_ws + XT_OFF);
    pre1<<<3072, 256, 0, stream>>>(w, style_w, style_b, conv_w, style, wsq);
    pre2<<<10816, 256, 0, stream>>>(x, style, wsq, conv_w, scale_bo, wtp2, xtp);
    dim3 grid(128, 4, 1);
    conv_mfma<<<grid, 512, 0, stream>>>(xtp, wtp2, scale_bo, noise,
                                        scale_noise, bias, out);
  } else {
    style_kernel<<<2048, 256, 0, stream>>>(w, style_w, style_b, style);
    wsq_kernel<<<1024, 256, 0, stream>>>(conv_w, wsq);
    scale_kernel<<<2048, 256, 0, stream>>>(style, wsq, scale_bo);
    dim3 grid(H_ / HTILE, COUT / OTILE, B_);
    conv_kernel<<<grid, 256, 0, stream>>>(x, style, conv_w, scale_bo,
                                          noise, scale_noise, bias, out);
  }
}